// Round 9
// baseline (170.848 us; speedup 1.0000x reference)
//
#include <hip/hip_runtime.h>
#include <hip/hip_bf16.h>

#define NB 32
#define NT 1024
#define ND 256
#define ETA 0.1f
#define INVS 0.70710678118654752440f

typedef short bf16x8 __attribute__((ext_vector_type(8)));
typedef float f32x4  __attribute__((ext_vector_type(4)));

__device__ inline unsigned short f2bf(float f){
  __hip_bfloat16 h = __float2bfloat16(f);
  return *reinterpret_cast<unsigned short*>(&h);
}
__device__ inline float bf2f(unsigned short u){
  return __uint_as_float(((unsigned int)u) << 16);
}
__device__ inline float4 bf2f4(ushort4 u){
  return make_float4(bf2f(u.x), bf2f(u.y), bf2f(u.z), bf2f(u.w));
}
__device__ inline ushort4 f2bf4(float4 v){
  ushort4 o; o.x = f2bf(v.x); o.y = f2bf(v.y); o.z = f2bf(v.z); o.w = f2bf(v.w); return o;
}

// ---- scalar Haar ladder (coarse kernels) ----
template<int N>
__device__ inline void idwt_lvl(float* a, const float* d){
#pragma unroll
  for (int i = N-1; i >= 0; --i){
    float av = a[i], dv = d[i];
    a[2*i]   = (av + dv) * INVS;
    a[2*i+1] = (av - dv) * INVS;
  }
}
template<int N>
__device__ inline void dwt_lvl(float* a, float* d){
#pragma unroll
  for (int i = 0; i < N; ++i){
    float e = a[2*i], o = a[2*i+1];
    a[i] = (e + o) * INVS;
    d[i] = (e - o) * INVS;
  }
}

// ---- float4 Haar ladder (fine kernels) ----
template<int N>
__device__ inline void idwt4_lvl(float4* a, const float4* dd){
#pragma unroll
  for (int i = N-1; i >= 0; --i){
    float4 av = a[i], dv = dd[i];
    a[2*i]   = make_float4((av.x+dv.x)*INVS, (av.y+dv.y)*INVS, (av.z+dv.z)*INVS, (av.w+dv.w)*INVS);
    a[2*i+1] = make_float4((av.x-dv.x)*INVS, (av.y-dv.y)*INVS, (av.z-dv.z)*INVS, (av.w-dv.w)*INVS);
  }
}
template<int N>
__device__ inline void dwt4_lvl(float4* a, float4* dd){
#pragma unroll
  for (int i = 0; i < N; ++i){
    float4 e = a[2*i], o = a[2*i+1];
    a[i]  = make_float4((e.x+o.x)*INVS, (e.y+o.y)*INVS, (e.z+o.z)*INVS, (e.w+o.w)*INVS);
    dd[i] = make_float4((e.x-o.x)*INVS, (e.y-o.y)*INVS, (e.z-o.z)*INVS, (e.w-o.w)*INVS);
  }
}

// ---------------- A: S = bf16(IDWT10(w*rho)); no LDS, no barriers ----------------
// block: (jg, b); thread: j = jg*4 + tid/64 (wave-uniform), d = (tid&63)*4
__global__ __launch_bounds__(256, 2) void k_idwt_first(const float* __restrict__ rho,
                                                       const float* __restrict__ w,
                                                       unsigned short* __restrict__ S){
  int b = blockIdx.y, jg = blockIdx.x, tid = threadIdx.x;
  int j = jg*4 + (tid >> 6);
  int d = (tid & 63) * 4;
  size_t cb = (size_t)b * NT * ND;

  // coarse leaf path: rows {0} + {(64>>l)+(j>>l)} for l=6..1
  float4 crho[7], cw[7];
  {
    int rows[7];
    rows[0] = 0;
#pragma unroll
    for (int l = 6; l >= 1; --l) rows[7-l] = (64 >> l) + (j >> l);
#pragma unroll
    for (int i = 0; i < 7; ++i){
      crho[i] = *(const float4*)(rho + cb + (size_t)rows[i]*ND + d);
      cw[i]   = *(const float4*)(w + (size_t)rows[i]*ND + d);
    }
  }
  // fine coefficient rows
  float4 frho[15], fw[15];
  {
    int fr[15];
    fr[0] = 64 + j;
#pragma unroll
    for (int i = 0; i < 2; ++i) fr[1+i] = 128 + 2*j + i;
#pragma unroll
    for (int i = 0; i < 4; ++i) fr[3+i] = 256 + 4*j + i;
#pragma unroll
    for (int i = 0; i < 8; ++i) fr[7+i] = 512 + 8*j + i;
#pragma unroll
    for (int i = 0; i < 15; ++i){
      frho[i] = *(const float4*)(rho + cb + (size_t)fr[i]*ND + d);
      fw[i]   = *(const float4*)(w + (size_t)fr[i]*ND + d);
    }
  }
  // coarse chain
  float4 a = make_float4(crho[0].x*cw[0].x, crho[0].y*cw[0].y, crho[0].z*cw[0].z, crho[0].w*cw[0].w);
#pragma unroll
  for (int l = 6; l >= 1; --l){
    float4 dv = crho[7-l]; float4 wv = cw[7-l];
    float s = ((j >> (l-1)) & 1) ? -INVS : INVS;
    a.x = a.x*INVS + dv.x*wv.x*s;
    a.y = a.y*INVS + dv.y*wv.y*s;
    a.z = a.z*INVS + dv.z*wv.z*s;
    a.w = a.w*INVS + dv.w*wv.w*s;
  }
  // fine ladder
  float4 f4v, f3[2], f2[4], f1[8];
  f4v = make_float4(frho[0].x*fw[0].x, frho[0].y*fw[0].y, frho[0].z*fw[0].z, frho[0].w*fw[0].w);
#pragma unroll
  for (int i = 0; i < 2; ++i) f3[i] = make_float4(frho[1+i].x*fw[1+i].x, frho[1+i].y*fw[1+i].y, frho[1+i].z*fw[1+i].z, frho[1+i].w*fw[1+i].w);
#pragma unroll
  for (int i = 0; i < 4; ++i) f2[i] = make_float4(frho[3+i].x*fw[3+i].x, frho[3+i].y*fw[3+i].y, frho[3+i].z*fw[3+i].z, frho[3+i].w*fw[3+i].w);
#pragma unroll
  for (int i = 0; i < 8; ++i) f1[i] = make_float4(frho[7+i].x*fw[7+i].x, frho[7+i].y*fw[7+i].y, frho[7+i].z*fw[7+i].z, frho[7+i].w*fw[7+i].w);

  float4 A[16];
  A[0] = a;
  idwt4_lvl<1>(A, &f4v); idwt4_lvl<2>(A, f3); idwt4_lvl<4>(A, f2); idwt4_lvl<8>(A, f1);
#pragma unroll
  for (int i = 0; i < 16; ++i)
    *(ushort4*)(S + cb + (size_t)(16*j + i)*ND + d) = f2bf4(A[i]);
}

// ---------------- C1: fine-DWT(Y); c' fine rows = blend(w*rho, details); stash chunk-approx ----------------
__global__ __launch_bounds__(256, 2) void k_mid_fine_dwt(const unsigned short* __restrict__ Y,
                                                         const float* __restrict__ rho,
                                                         const float* __restrict__ w,
                                                         float* __restrict__ c,
                                                         float* __restrict__ st1){
  int b = blockIdx.y, jg = blockIdx.x, tid = threadIdx.x;
  int j = jg*4 + (tid >> 6);
  int d = (tid & 63) * 4;
  size_t cb = (size_t)b * NT * ND;

  ushort4 yv[16];
#pragma unroll
  for (int i = 0; i < 16; ++i)
    yv[i] = *(const ushort4*)(Y + cb + (size_t)(16*j + i)*ND + d);

  int fr[15];
  fr[0] = 64 + j;
#pragma unroll
  for (int i = 0; i < 2; ++i) fr[1+i] = 128 + 2*j + i;
#pragma unroll
  for (int i = 0; i < 4; ++i) fr[3+i] = 256 + 4*j + i;
#pragma unroll
  for (int i = 0; i < 8; ++i) fr[7+i] = 512 + 8*j + i;
  float4 rr[15], ww[15];
#pragma unroll
  for (int i = 0; i < 15; ++i){
    rr[i] = *(const float4*)(rho + cb + (size_t)fr[i]*ND + d);
    ww[i] = *(const float4*)(w + (size_t)fr[i]*ND + d);
  }

  float4 x[16];
#pragma unroll
  for (int i = 0; i < 16; ++i) x[i] = bf2f4(yv[i]);
  float4 d1[8], d2[4], d3[2], d4v;
  dwt4_lvl<8>(x, d1); dwt4_lvl<4>(x, d2); dwt4_lvl<2>(x, d3); dwt4_lvl<1>(x, &d4v);

  *(float4*)(st1 + ((size_t)b*64 + j)*256 + d) = x[0];

  float4 det[15];
  det[0] = d4v;
#pragma unroll
  for (int i = 0; i < 2; ++i) det[1+i] = d3[i];
#pragma unroll
  for (int i = 0; i < 4; ++i) det[3+i] = d2[i];
#pragma unroll
  for (int i = 0; i < 8; ++i) det[7+i] = d1[i];
#pragma unroll
  for (int i = 0; i < 15; ++i){
    float4 cv = make_float4(rr[i].x*ww[i].x, rr[i].y*ww[i].y, rr[i].z*ww[i].z, rr[i].w*ww[i].w);
    float4 nc = make_float4(cv.x - ETA*(cv.x - det[i].x),
                            cv.y - ETA*(cv.y - det[i].y),
                            cv.z - ETA*(cv.z - det[i].z),
                            cv.w - ETA*(cv.w - det[i].w));
    *(float4*)(c + cb + (size_t)fr[i]*ND + d) = nc;
  }
}

// ---------------- C2: coarse DWT of stash, blend -> c' rows 0..63, coarse IDWT -> A4n ----------------
__global__ __launch_bounds__(256, 1) void k_mid_coarse(const float* __restrict__ st1,
                                                       const float* __restrict__ rho,
                                                       const float* __restrict__ w,
                                                       float* __restrict__ c,
                                                       float* __restrict__ a4n){
  int b = blockIdx.x;
  int d = threadIdx.x;
  size_t cb = (size_t)b * NT * ND;
  float x[64];
#pragma unroll
  for (int j = 0; j < 64; ++j) x[j] = st1[((size_t)b*64 + j)*256 + d];
  float y[64];
  dwt_lvl<32>(x, y+32); dwt_lvl<16>(x, y+16); dwt_lvl<8>(x, y+8);
  dwt_lvl<4>(x, y+4);   dwt_lvl<2>(x, y+2);   dwt_lvl<1>(x, y+1);
  y[0] = x[0];
  float nc[64];
#pragma unroll
  for (int r = 0; r < 64; ++r){
    float cv = rho[cb + (size_t)r*ND + d] * w[(size_t)r*ND + d];
    nc[r] = cv - ETA*(cv - y[r]);
    c[cb + (size_t)r*ND + d] = nc[r];
  }
  float a[64];
  a[0] = nc[0];
  idwt_lvl<1>(a, nc+1);  idwt_lvl<2>(a, nc+2);   idwt_lvl<4>(a, nc+4);
  idwt_lvl<8>(a, nc+8);  idwt_lvl<16>(a, nc+16); idwt_lvl<32>(a, nc+32);
#pragma unroll
  for (int j = 0; j < 64; ++j) a4n[((size_t)b*64 + j)*256 + d] = a[j];
}

// ---------------- C3: fine-IDWT(A4n, c' fine rows) -> S ----------------
__global__ __launch_bounds__(256, 2) void k_mid_idwt(const float* __restrict__ a4n,
                                                     const float* __restrict__ c,
                                                     unsigned short* __restrict__ S){
  int b = blockIdx.y, jg = blockIdx.x, tid = threadIdx.x;
  int j = jg*4 + (tid >> 6);
  int d = (tid & 63) * 4;
  size_t cb = (size_t)b * NT * ND;

  float4 a = *(const float4*)(a4n + ((size_t)b*64 + j)*256 + d);
  float4 f4v = *(const float4*)(c + cb + (size_t)(64 + j)*ND + d);
  float4 f3[2], f2[4], f1[8];
#pragma unroll
  for (int i = 0; i < 2; ++i) f3[i] = *(const float4*)(c + cb + (size_t)(128 + 2*j + i)*ND + d);
#pragma unroll
  for (int i = 0; i < 4; ++i) f2[i] = *(const float4*)(c + cb + (size_t)(256 + 4*j + i)*ND + d);
#pragma unroll
  for (int i = 0; i < 8; ++i) f1[i] = *(const float4*)(c + cb + (size_t)(512 + 8*j + i)*ND + d);

  float4 A[16];
  A[0] = a;
  idwt4_lvl<1>(A, &f4v); idwt4_lvl<2>(A, f3); idwt4_lvl<4>(A, f2); idwt4_lvl<8>(A, f1);
#pragma unroll
  for (int i = 0; i < 16; ++i)
    *(ushort4*)(S + cb + (size_t)(16*j + i)*ND + d) = f2bf4(A[i]);
}

// ---------------- E1: fine-DWT(Y2); out fine rows = blend(c', det)/w; stash2 ----------------
__global__ __launch_bounds__(256, 2) void k_fin_fine(const unsigned short* __restrict__ Y,
                                                     const float* __restrict__ w,
                                                     float* __restrict__ c,
                                                     float* __restrict__ st2){
  int b = blockIdx.y, jg = blockIdx.x, tid = threadIdx.x;
  int j = jg*4 + (tid >> 6);
  int d = (tid & 63) * 4;
  size_t cb = (size_t)b * NT * ND;

  ushort4 yv[16];
#pragma unroll
  for (int i = 0; i < 16; ++i)
    yv[i] = *(const ushort4*)(Y + cb + (size_t)(16*j + i)*ND + d);

  int fr[15];
  fr[0] = 64 + j;
#pragma unroll
  for (int i = 0; i < 2; ++i) fr[1+i] = 128 + 2*j + i;
#pragma unroll
  for (int i = 0; i < 4; ++i) fr[3+i] = 256 + 4*j + i;
#pragma unroll
  for (int i = 0; i < 8; ++i) fr[7+i] = 512 + 8*j + i;
  float4 cc[15], ww[15];
#pragma unroll
  for (int i = 0; i < 15; ++i){
    cc[i] = *(const float4*)(c + cb + (size_t)fr[i]*ND + d);
    ww[i] = *(const float4*)(w + (size_t)fr[i]*ND + d);
  }

  float4 x[16];
#pragma unroll
  for (int i = 0; i < 16; ++i) x[i] = bf2f4(yv[i]);
  float4 d1[8], d2[4], d3[2], d4v;
  dwt4_lvl<8>(x, d1); dwt4_lvl<4>(x, d2); dwt4_lvl<2>(x, d3); dwt4_lvl<1>(x, &d4v);

  *(float4*)(st2 + ((size_t)b*64 + j)*256 + d) = x[0];

  float4 det[15];
  det[0] = d4v;
#pragma unroll
  for (int i = 0; i < 2; ++i) det[1+i] = d3[i];
#pragma unroll
  for (int i = 0; i < 4; ++i) det[3+i] = d2[i];
#pragma unroll
  for (int i = 0; i < 8; ++i) det[7+i] = d1[i];
#pragma unroll
  for (int i = 0; i < 15; ++i){
    float4 cv = cc[i];
    float4 ov = make_float4((cv.x - ETA*(cv.x - det[i].x)) / ww[i].x,
                            (cv.y - ETA*(cv.y - det[i].y)) / ww[i].y,
                            (cv.z - ETA*(cv.z - det[i].z)) / ww[i].z,
                            (cv.w - ETA*(cv.w - det[i].w)) / ww[i].w);
    *(float4*)(c + cb + (size_t)fr[i]*ND + d) = ov;
  }
}

// ---------------- E2: coarse DWT of stash2; out rows 0..63 = blend(c', y)/w ----------------
__global__ __launch_bounds__(256, 1) void k_fin_coarse(const float* __restrict__ st2,
                                                       const float* __restrict__ w,
                                                       float* __restrict__ c){
  int b = blockIdx.x;
  int d = threadIdx.x;
  size_t cb = (size_t)b * NT * ND;
  float x[64];
#pragma unroll
  for (int j = 0; j < 64; ++j) x[j] = st2[((size_t)b*64 + j)*256 + d];
  float y[64];
  dwt_lvl<32>(x, y+32); dwt_lvl<16>(x, y+16); dwt_lvl<8>(x, y+8);
  dwt_lvl<4>(x, y+4);   dwt_lvl<2>(x, y+2);   dwt_lvl<1>(x, y+1);
  y[0] = x[0];
#pragma unroll
  for (int r = 0; r < 64; ++r){
    float cv = c[cb + (size_t)r*ND + d];
    c[cb + (size_t)r*ND + d] = (cv - ETA*(cv - y[r])) / w[(size_t)r*ND + d];
  }
}

// ---------------- per-band GEMM, register-held B panel, TM=2 tiles/block ----------------
__global__ __launch_bounds__(256, 2) void k_band_gemm(const unsigned short* __restrict__ S,
                                                      const unsigned short* __restrict__ Wt,
                                                      const float* __restrict__ bias,
                                                      unsigned short* __restrict__ Y){
  int bx = blockIdx.x;  // 0..591
  int wv = threadIdx.x >> 6, lane = threadIdx.x & 63;
  int row = lane & 15, kg = lane >> 4;
  int band, jbase; bool masked = false;
  if      (bx <  16){ band =  6; jbase = bx*2; }
  else if (bx <  48){ band =  7; jbase = (bx-16)*2; }
  else if (bx < 112){ band =  8; jbase = (bx-48)*2; }
  else if (bx < 240){ band =  9; jbase = (bx-112)*2; }
  else if (bx < 496){ band = 10; jbase = (bx-240)*2; }
  else { masked = true; int mb = bx-496; band = mb>>4; jbase = (mb&15)*2; }

  int n0 = wv * 64;
  const unsigned short* Wb = Wt + (size_t)band * 65536;

  bf16x8 breg[8][4];
#pragma unroll
  for (int kk = 0; kk < 8; ++kk)
#pragma unroll
    for (int ni = 0; ni < 4; ++ni)
      breg[kk][ni] = *(const bf16x8*)(Wb + (size_t)(n0 + 16*ni + row)*256 + kk*32 + kg*8);

  float bv[4];
#pragma unroll
  for (int ni = 0; ni < 4; ++ni) bv[ni] = bias[band*256 + n0 + 16*ni + row];

  int lo = 0, hi = 0;
  if (masked){
    lo = (band == 0) ? 0 : (1 << (band - 1));
    hi = (band == 0) ? 1 : (1 << band);
  }
  int shift = masked ? 0 : (band - 6);
  int tstart = masked ? 0 : (32 << shift);

  for (int m = 0; m < 2; ++m){
    int j = jbase + m;
    int bb, t0;
    if (masked){ bb = j; t0 = 0; }
    else { bb = j >> shift; t0 = tstart + (j & ((1 << shift) - 1)) * 32; }

    f32x4 acc[2][4];
#pragma unroll
    for (int mi = 0; mi < 2; ++mi)
#pragma unroll
      for (int ni = 0; ni < 4; ++ni) acc[mi][ni] = (f32x4){0.f, 0.f, 0.f, 0.f};

    size_t arow0 = ((size_t)bb * NT + t0 + row) * ND;
#pragma unroll
    for (int kk = 0; kk < 8; ++kk){
      int k = kk*32 + kg*8;
      bf16x8 a0 = *(const bf16x8*)(S + arow0 + k);
      bf16x8 a1 = *(const bf16x8*)(S + arow0 + 16*ND + k);
#pragma unroll
      for (int ni = 0; ni < 4; ++ni){
        acc[0][ni] = __builtin_amdgcn_mfma_f32_16x16x32_bf16(a0, breg[kk][ni], acc[0][ni], 0, 0, 0);
        acc[1][ni] = __builtin_amdgcn_mfma_f32_16x16x32_bf16(a1, breg[kk][ni], acc[1][ni], 0, 0, 0);
      }
    }
#pragma unroll
    for (int ni = 0; ni < 4; ++ni){
#pragma unroll
      for (int mi = 0; mi < 2; ++mi){
#pragma unroll
        for (int jj = 0; jj < 4; ++jj){
          int t = t0 + 16*mi + kg*4 + jj;   // C/D: row=(lane>>4)*4+reg, col=lane&15
          if (!masked || (t >= lo && t < hi)){
            Y[((size_t)bb*NT + t)*ND + n0 + 16*ni + row] = f2bf(acc[mi][ni][jj] + bv[ni]);
          }
        }
      }
    }
  }
}

// ---------------- Wt[band][e][d] = bf16(W[band][d][e]) ----------------
__global__ __launch_bounds__(256) void k_wprep(const float* __restrict__ W,
                                               unsigned short* __restrict__ Wt){
  __shared__ float tbuf[32][33];
  int band = blockIdx.y;
  int tile = blockIdx.x;             // 0..63 -> 8x8 grid of 32x32 tiles
  int td0 = (tile >> 3) * 32, te0 = (tile & 7) * 32;
  int tx = threadIdx.x & 31, ty = threadIdx.x >> 5;
#pragma unroll
  for (int i = 0; i < 4; ++i){
    tbuf[ty*4 + i][tx] = W[(size_t)band*65536 + (size_t)(td0 + ty*4 + i)*256 + te0 + tx];
  }
  __syncthreads();
#pragma unroll
  for (int i = 0; i < 4; ++i){
    Wt[(size_t)band*65536 + (size_t)(te0 + ty*4 + i)*256 + td0 + tx] = f2bf(tbuf[tx][ty*4 + i]);
  }
}

extern "C" void kernel_launch(void* const* d_in, const int* in_sizes, int n_in,
                              void* d_out, int out_size, void* d_ws, size_t ws_size,
                              hipStream_t stream){
  const float* rho  = (const float*)d_in[0];
  const float* w    = (const float*)d_in[1];
  const float* W    = (const float*)d_in[2];
  const float* bias = (const float*)d_in[3];

  float* c = (float*)d_out;                                   // coeff state / output
  unsigned short* S  = (unsigned short*)d_ws;                 // 16 MB bf16 signal
  unsigned short* Y  = S + (size_t)NB * NT * ND;              // 16 MB bf16 predicted signal
  unsigned short* Wt = Y + (size_t)NB * NT * ND;              // 1.4 MB bf16 transposed weights
  // 2 MB stash buffers alias dead buffer heads (lifetimes verified):
  float* st1 = (float*)S;   // written by C1 (S dead after gemm1), read by C2, clobbered by C3's S write
  float* a4n = (float*)Y;   // written by C2 (Y dead after C1), read by C3, clobbered by gemm2's Y write
  float* st2 = (float*)S;   // written by E1 (S dead after gemm2), read by E2

  k_wprep<<<dim3(64, 11), 256, 0, stream>>>(W, Wt);
  k_idwt_first<<<dim3(16, NB), 256, 0, stream>>>(rho, w, S);
  k_band_gemm<<<592, 256, 0, stream>>>(S, Wt, bias, Y);
  k_mid_fine_dwt<<<dim3(16, NB), 256, 0, stream>>>(Y, rho, w, c, st1);
  k_mid_coarse<<<NB, 256, 0, stream>>>(st1, rho, w, c, a4n);
  k_mid_idwt<<<dim3(16, NB), 256, 0, stream>>>(a4n, c, S);
  k_band_gemm<<<592, 256, 0, stream>>>(S, Wt, bias, Y);
  k_fin_fine<<<dim3(16, NB), 256, 0, stream>>>(Y, w, c, st2);
  k_fin_coarse<<<NB, 256, 0, stream>>>(st2, w, c);
}

// Round 10
// 128.719 us; speedup vs baseline: 1.3273x; 1.3273x over previous
//
#include <hip/hip_runtime.h>
#include <hip/hip_bf16.h>

#define NB 32
#define NT 1024
#define ND 256
#define ETA 0.1f
#define INVS 0.70710678118654752440f

typedef short bf16x8 __attribute__((ext_vector_type(8)));
typedef float f32x4  __attribute__((ext_vector_type(4)));
typedef float f32x2  __attribute__((ext_vector_type(2)));

__device__ inline unsigned short f2bf(float f){
  __hip_bfloat16 h = __float2bfloat16(f);
  return *reinterpret_cast<unsigned short*>(&h);
}
__device__ inline f32x2 bfp2f(unsigned u){          // bf16 pair -> float2
  return (f32x2){ __uint_as_float(u << 16), __uint_as_float(u & 0xffff0000u) };
}
__device__ inline unsigned pack_bf2(f32x2 v){       // float2 -> bf16 pair (RNE)
  return ((unsigned)f2bf(v.y) << 16) | (unsigned)f2bf(v.x);
}

// ---- generic in-register Haar ladders (compile-time indices) ----
template<int N, typename T>
__device__ inline void idwtT(T* a, const T* d){
#pragma unroll
  for (int i = N-1; i >= 0; --i){
    T av = a[i], dv = d[i];
    a[2*i]   = (av + dv) * INVS;
    a[2*i+1] = (av - dv) * INVS;
  }
}
template<int N, typename T>
__device__ inline void dwtT(T* a, T* d){
#pragma unroll
  for (int i = 0; i < N; ++i){
    T e = a[2*i], o = a[2*i+1];
    a[i] = (e + o) * INVS;
    d[i] = (e - o) * INVS;
  }
}
// in-place DWT level with path-detail + own-row selection (no dynamic reg indexing)
template<int N>
__device__ inline void dwt_sel(float* x, int pj, float& pdet, int j, float& yj){
#pragma unroll
  for (int i = 0; i < N; ++i){
    float e = x[2*i], o = x[2*i+1];
    float aa = (e + o) * INVS, dd = (e - o) * INVS;
    x[i] = aa;
    if (i == pj)    pdet = dd;
    if (N + i == j) yj   = dd;
  }
}

__device__ inline void fine_rows(int j, int* fr){
  fr[0] = 64 + j;
#pragma unroll
  for (int i = 0; i < 2; ++i) fr[1+i] = 128 + 2*j + i;
#pragma unroll
  for (int i = 0; i < 4; ++i) fr[3+i] = 256 + 4*j + i;
#pragma unroll
  for (int i = 0; i < 8; ++i) fr[7+i] = 512 + 8*j + i;
}

// ---------------- K1: S = bf16(IDWT10(w*rho)) ; per-thread (j, d2) ----------------
__global__ __launch_bounds__(256, 3) void k_first(const float* __restrict__ rho,
                                                  const float* __restrict__ w,
                                                  unsigned* __restrict__ S2){
  int b = blockIdx.y, tid = threadIdx.x;
  int j = blockIdx.x*2 + (tid >> 7);
  int dq = tid & 127;                       // d = dq*2
  size_t cb = (size_t)b*NT*ND;
  size_t sb = (size_t)b*NT*128;             // uint units

  // coarse leaf (7 rows)
  f32x2 cr[7], cw[7];
  int crow[7]; crow[0] = 0;
#pragma unroll
  for (int l = 6; l >= 1; --l) crow[7-l] = (64>>l) + (j>>l);
#pragma unroll
  for (int i = 0; i < 7; ++i){
    cr[i] = *(const f32x2*)(rho + cb + (size_t)crow[i]*ND + dq*2);
    cw[i] = *(const f32x2*)(w + (size_t)crow[i]*ND + dq*2);
  }
  f32x2 a = cr[0]*cw[0];
#pragma unroll
  for (int l = 6; l >= 1; --l){
    float s = ((j>>(l-1)) & 1) ? -INVS : INVS;
    a = a*INVS + (cr[7-l]*cw[7-l])*s;
  }
  // fine rows
  int fr[15]; fine_rows(j, fr);
  f32x2 rr[15], ww[15];
#pragma unroll
  for (int i = 0; i < 15; ++i){
    rr[i] = *(const f32x2*)(rho + cb + (size_t)fr[i]*ND + dq*2);
    ww[i] = *(const f32x2*)(w + (size_t)fr[i]*ND + dq*2);
  }
  f32x2 f4v = rr[0]*ww[0];
  f32x2 f3[2], f2a[4], f1[8];
#pragma unroll
  for (int i = 0; i < 2; ++i) f3[i]  = rr[1+i]*ww[1+i];
#pragma unroll
  for (int i = 0; i < 4; ++i) f2a[i] = rr[3+i]*ww[3+i];
#pragma unroll
  for (int i = 0; i < 8; ++i) f1[i]  = rr[7+i]*ww[7+i];

  f32x2 A[16]; A[0] = a;
  idwtT<1>(A, &f4v); idwtT<2>(A, f3); idwtT<4>(A, f2a); idwtT<8>(A, f1);
#pragma unroll
  for (int i = 0; i < 16; ++i)
    S2[sb + (size_t)(16*j + i)*128 + dq] = pack_bf2(A[i]);
}

// ---------------- K3: fine-DWT(Y); c fine rows = blend(w*rho, det); stash chunk approx ----------------
__global__ __launch_bounds__(256, 3) void k_mid1(const unsigned* __restrict__ Y2,
                                                 const float* __restrict__ rho,
                                                 const float* __restrict__ w,
                                                 float* __restrict__ c,
                                                 float* __restrict__ st1){
  int b = blockIdx.y, tid = threadIdx.x;
  int j = blockIdx.x*2 + (tid >> 7);
  int dq = tid & 127;
  size_t cb = (size_t)b*NT*ND;
  size_t sb = (size_t)b*NT*128;

  unsigned yv[16];
#pragma unroll
  for (int i = 0; i < 16; ++i) yv[i] = Y2[sb + (size_t)(16*j + i)*128 + dq];

  int fr[15]; fine_rows(j, fr);
  f32x2 rr[15], ww[15];
#pragma unroll
  for (int i = 0; i < 15; ++i){
    rr[i] = *(const f32x2*)(rho + cb + (size_t)fr[i]*ND + dq*2);
    ww[i] = *(const f32x2*)(w + (size_t)fr[i]*ND + dq*2);
  }

  f32x2 x[16];
#pragma unroll
  for (int i = 0; i < 16; ++i) x[i] = bfp2f(yv[i]);
  f32x2 d1[8], d2v[4], d3[2], d4v;
  dwtT<8>(x, d1); dwtT<4>(x, d2v); dwtT<2>(x, d3); dwtT<1>(x, &d4v);

  *(f32x2*)(st1 + ((size_t)b*64 + j)*ND + dq*2) = x[0];

  f32x2 det[15];
  det[0] = d4v;
#pragma unroll
  for (int i = 0; i < 2; ++i) det[1+i] = d3[i];
#pragma unroll
  for (int i = 0; i < 4; ++i) det[3+i] = d2v[i];
#pragma unroll
  for (int i = 0; i < 8; ++i) det[7+i] = d1[i];
#pragma unroll
  for (int i = 0; i < 15; ++i){
    f32x2 cv = rr[i]*ww[i];
    f32x2 nc = cv - (cv - det[i])*ETA;
    *(f32x2*)(c + cb + (size_t)fr[i]*ND + dq*2) = nc;
  }
}

// ---------------- K4: coarse (in-reg, redundant per j) + fine IDWT -> S ; writes c' coarse row j ----------------
__global__ __launch_bounds__(256, 3) void k_mid2(const float* __restrict__ st1,
                                                 const float* __restrict__ rho,
                                                 const float* __restrict__ w,
                                                 float* __restrict__ c,
                                                 unsigned short* __restrict__ S){
  int b = blockIdx.y, j = blockIdx.x, d = threadIdx.x;
  size_t cb = (size_t)b*NT*ND;

  float x[64];
#pragma unroll
  for (int k = 0; k < 64; ++k) x[k] = st1[((size_t)b*64 + k)*ND + d];

  // path rho/w rows (uniform, L2-hot)
  float prr[7], pww[7];
  prr[0] = rho[cb + d]; pww[0] = w[d];
#pragma unroll
  for (int l = 6; l >= 1; --l){
    int r = (64>>l) + (j>>l);
    prr[7-l] = rho[cb + (size_t)r*ND + d];
    pww[7-l] = w[(size_t)r*ND + d];
  }
  // own-row rho/w (row j)
  float orr = rho[cb + (size_t)j*ND + d];
  float oww = w[(size_t)j*ND + d];
  // fine c' rows (from k_mid1)
  int fr[15]; fine_rows(j, fr);
  float cf[15];
#pragma unroll
  for (int i = 0; i < 15; ++i) cf[i] = c[cb + (size_t)fr[i]*ND + d];

  // in-place coarse DWT with selections
  float pd[6]; float yj = 0.f;
  dwt_sel<32>(x, j>>1, pd[0], j, yj);
  dwt_sel<16>(x, j>>2, pd[1], j, yj);
  dwt_sel< 8>(x, j>>3, pd[2], j, yj);
  dwt_sel< 4>(x, j>>4, pd[3], j, yj);
  dwt_sel< 2>(x, j>>5, pd[4], j, yj);
  dwt_sel< 1>(x, j>>6, pd[5], j, yj);
  if (j == 0) yj = x[0];

  // c' coarse row j
  {
    float cv = orr*oww;
    c[cb + (size_t)j*ND + d] = cv - ETA*(cv - yj);
  }
  // blended leaf walk
  float cv0 = prr[0]*pww[0];
  float a = cv0 - ETA*(cv0 - x[0]);
#pragma unroll
  for (int l = 6; l >= 1; --l){
    float cv = prr[7-l]*pww[7-l];
    float ncl = cv - ETA*(cv - pd[l-1]);
    float s = ((j>>(l-1)) & 1) ? -1.f : 1.f;
    a = (a + s*ncl)*INVS;
  }
  // fine IDWT from c' fine rows
  float f4v = cf[0];
  float f3[2], f2a[4], f1[8];
#pragma unroll
  for (int i = 0; i < 2; ++i) f3[i]  = cf[1+i];
#pragma unroll
  for (int i = 0; i < 4; ++i) f2a[i] = cf[3+i];
#pragma unroll
  for (int i = 0; i < 8; ++i) f1[i]  = cf[7+i];
  float A[16]; A[0] = a;
  idwtT<1>(A, &f4v); idwtT<2>(A, f3); idwtT<4>(A, f2a); idwtT<8>(A, f1);
#pragma unroll
  for (int i = 0; i < 16; ++i)
    S[cb + (size_t)(16*j + i)*ND + d] = f2bf(A[i]);
}

// ---------------- K6: fine-DWT(Y2); out fine rows = blend(c',det)/w ; stash2 ----------------
__global__ __launch_bounds__(256, 3) void k_fin1(const unsigned* __restrict__ Y2,
                                                 const float* __restrict__ w,
                                                 float* __restrict__ c,
                                                 float* __restrict__ st2){
  int b = blockIdx.y, tid = threadIdx.x;
  int j = blockIdx.x*2 + (tid >> 7);
  int dq = tid & 127;
  size_t cb = (size_t)b*NT*ND;
  size_t sb = (size_t)b*NT*128;

  unsigned yv[16];
#pragma unroll
  for (int i = 0; i < 16; ++i) yv[i] = Y2[sb + (size_t)(16*j + i)*128 + dq];

  int fr[15]; fine_rows(j, fr);
  f32x2 cc[15], ww[15];
#pragma unroll
  for (int i = 0; i < 15; ++i){
    cc[i] = *(const f32x2*)(c + cb + (size_t)fr[i]*ND + dq*2);
    ww[i] = *(const f32x2*)(w + (size_t)fr[i]*ND + dq*2);
  }

  f32x2 x[16];
#pragma unroll
  for (int i = 0; i < 16; ++i) x[i] = bfp2f(yv[i]);
  f32x2 d1[8], d2v[4], d3[2], d4v;
  dwtT<8>(x, d1); dwtT<4>(x, d2v); dwtT<2>(x, d3); dwtT<1>(x, &d4v);

  *(f32x2*)(st2 + ((size_t)b*64 + j)*ND + dq*2) = x[0];

  f32x2 det[15];
  det[0] = d4v;
#pragma unroll
  for (int i = 0; i < 2; ++i) det[1+i] = d3[i];
#pragma unroll
  for (int i = 0; i < 4; ++i) det[3+i] = d2v[i];
#pragma unroll
  for (int i = 0; i < 8; ++i) det[7+i] = d1[i];
#pragma unroll
  for (int i = 0; i < 15; ++i){
    f32x2 cv = cc[i];
    f32x2 ov = (cv - (cv - det[i])*ETA) / ww[i];
    *(f32x2*)(c + cb + (size_t)fr[i]*ND + dq*2) = ov;
  }
}

// ---------------- K7: coarse finish — out coarse row j from stash2 ----------------
__global__ __launch_bounds__(256, 4) void k_fin2(const float* __restrict__ st2,
                                                 const float* __restrict__ w,
                                                 float* __restrict__ c){
  int b = blockIdx.y, j = blockIdx.x, d = threadIdx.x;
  size_t cb = (size_t)b*NT*ND;

  float x[64];
#pragma unroll
  for (int k = 0; k < 64; ++k) x[k] = st2[((size_t)b*64 + k)*ND + d];

  float cj = c[cb + (size_t)j*ND + d];       // c' coarse row j (from k_mid2)
  float wj = w[(size_t)j*ND + d];

  float dummy = 0.f; float yj = 0.f;
  dwt_sel<32>(x, -1, dummy, j, yj);
  dwt_sel<16>(x, -1, dummy, j, yj);
  dwt_sel< 8>(x, -1, dummy, j, yj);
  dwt_sel< 4>(x, -1, dummy, j, yj);
  dwt_sel< 2>(x, -1, dummy, j, yj);
  dwt_sel< 1>(x, -1, dummy, j, yj);
  if (j == 0) yj = x[0];

  c[cb + (size_t)j*ND + d] = (cj - ETA*(cj - yj)) / wj;
}

// ---------------- per-band GEMM, register-held B panel, TM=2 tiles/block ----------------
__global__ __launch_bounds__(256, 2) void k_band_gemm(const unsigned short* __restrict__ S,
                                                      const unsigned short* __restrict__ Wt,
                                                      const float* __restrict__ bias,
                                                      unsigned short* __restrict__ Y){
  int bx = blockIdx.x;  // 0..591
  int wv = threadIdx.x >> 6, lane = threadIdx.x & 63;
  int row = lane & 15, kg = lane >> 4;
  int band, jbase; bool masked = false;
  if      (bx <  16){ band =  6; jbase = bx*2; }
  else if (bx <  48){ band =  7; jbase = (bx-16)*2; }
  else if (bx < 112){ band =  8; jbase = (bx-48)*2; }
  else if (bx < 240){ band =  9; jbase = (bx-112)*2; }
  else if (bx < 496){ band = 10; jbase = (bx-240)*2; }
  else { masked = true; int mb = bx-496; band = mb>>4; jbase = (mb&15)*2; }

  int n0 = wv * 64;
  const unsigned short* Wb = Wt + (size_t)band * 65536;

  bf16x8 breg[8][4];
#pragma unroll
  for (int kk = 0; kk < 8; ++kk)
#pragma unroll
    for (int ni = 0; ni < 4; ++ni)
      breg[kk][ni] = *(const bf16x8*)(Wb + (size_t)(n0 + 16*ni + row)*256 + kk*32 + kg*8);

  float bv[4];
#pragma unroll
  for (int ni = 0; ni < 4; ++ni) bv[ni] = bias[band*256 + n0 + 16*ni + row];

  int lo = 0, hi = 0;
  if (masked){
    lo = (band == 0) ? 0 : (1 << (band - 1));
    hi = (band == 0) ? 1 : (1 << band);
  }
  int shift = masked ? 0 : (band - 6);
  int tstart = masked ? 0 : (32 << shift);

  for (int m = 0; m < 2; ++m){
    int j = jbase + m;
    int bb, t0;
    if (masked){ bb = j; t0 = 0; }
    else { bb = j >> shift; t0 = tstart + (j & ((1 << shift) - 1)) * 32; }

    f32x4 acc[2][4];
#pragma unroll
    for (int mi = 0; mi < 2; ++mi)
#pragma unroll
      for (int ni = 0; ni < 4; ++ni) acc[mi][ni] = (f32x4){0.f, 0.f, 0.f, 0.f};

    size_t arow0 = ((size_t)bb * NT + t0 + row) * ND;
#pragma unroll
    for (int kk = 0; kk < 8; ++kk){
      int k = kk*32 + kg*8;
      bf16x8 a0 = *(const bf16x8*)(S + arow0 + k);
      bf16x8 a1 = *(const bf16x8*)(S + arow0 + 16*ND + k);
#pragma unroll
      for (int ni = 0; ni < 4; ++ni){
        acc[0][ni] = __builtin_amdgcn_mfma_f32_16x16x32_bf16(a0, breg[kk][ni], acc[0][ni], 0, 0, 0);
        acc[1][ni] = __builtin_amdgcn_mfma_f32_16x16x32_bf16(a1, breg[kk][ni], acc[1][ni], 0, 0, 0);
      }
    }
#pragma unroll
    for (int ni = 0; ni < 4; ++ni){
#pragma unroll
      for (int mi = 0; mi < 2; ++mi){
#pragma unroll
        for (int jj = 0; jj < 4; ++jj){
          int t = t0 + 16*mi + kg*4 + jj;   // C/D: row=(lane>>4)*4+reg, col=lane&15
          if (!masked || (t >= lo && t < hi)){
            Y[((size_t)bb*NT + t)*ND + n0 + 16*ni + row] = f2bf(acc[mi][ni][jj] + bv[ni]);
          }
        }
      }
    }
  }
}

// ---------------- Wt[band][e][d] = bf16(W[band][d][e]) ----------------
__global__ __launch_bounds__(256) void k_wprep(const float* __restrict__ W,
                                               unsigned short* __restrict__ Wt){
  __shared__ float tbuf[32][33];
  int band = blockIdx.y;
  int tile = blockIdx.x;             // 0..63 -> 8x8 grid of 32x32 tiles
  int td0 = (tile >> 3) * 32, te0 = (tile & 7) * 32;
  int tx = threadIdx.x & 31, ty = threadIdx.x >> 5;
#pragma unroll
  for (int i = 0; i < 4; ++i){
    tbuf[ty*4 + i][tx] = W[(size_t)band*65536 + (size_t)(td0 + ty*4 + i)*256 + te0 + tx];
  }
  __syncthreads();
#pragma unroll
  for (int i = 0; i < 4; ++i){
    Wt[(size_t)band*65536 + (size_t)(te0 + ty*4 + i)*256 + td0 + tx] = f2bf(tbuf[tx][ty*4 + i]);
  }
}

extern "C" void kernel_launch(void* const* d_in, const int* in_sizes, int n_in,
                              void* d_out, int out_size, void* d_ws, size_t ws_size,
                              hipStream_t stream){
  const float* rho  = (const float*)d_in[0];
  const float* w    = (const float*)d_in[1];
  const float* W    = (const float*)d_in[2];
  const float* bias = (const float*)d_in[3];

  float* c = (float*)d_out;                                   // coeff state / output
  unsigned short* S  = (unsigned short*)d_ws;                 // 16.8 MB bf16 signal
  unsigned short* Y  = S + (size_t)NB * NT * ND;              // 16.8 MB bf16 predicted signal
  unsigned short* Wt = Y + (size_t)NB * NT * ND;              // 1.44 MB bf16 transposed weights
  float* st1 = (float*)(Wt + (size_t)11 * 65536);             // 2 MB [b][64][256]
  float* st2 = st1 + (size_t)NB * 64 * ND;                    // 2 MB [b][64][256]

  k_wprep<<<dim3(64, 11), 256, 0, stream>>>(W, Wt);
  k_first<<<dim3(32, NB), 256, 0, stream>>>(rho, w, (unsigned*)S);
  k_band_gemm<<<592, 256, 0, stream>>>(S, Wt, bias, Y);
  k_mid1<<<dim3(32, NB), 256, 0, stream>>>((const unsigned*)Y, rho, w, c, st1);
  k_mid2<<<dim3(64, NB), 256, 0, stream>>>(st1, rho, w, c, S);
  k_band_gemm<<<592, 256, 0, stream>>>(S, Wt, bias, Y);
  k_fin1<<<dim3(32, NB), 256, 0, stream>>>((const unsigned*)Y, w, c, st2);
  k_fin2<<<dim3(64, NB), 256, 0, stream>>>(st2, w, c);
}